// Round 3
// baseline (126.131 us; speedup 1.0000x reference)
//
#include <hip/hip_runtime.h>
#include <math.h>

#define G_TOT   16380
#define N_NODES 10242
#define LATN    91
#define LONN    180
#define CH      64
#define NBATCH  4
#define KNN     8

#define NW      8                    // waves per knn block
#define CAP     1472                 // LDS candidate capacity (expected ~300)
#define TLA     8
#define TLO     8
#define NTI     12                   // ceil(91/8)
#define NTJ     23                   // ceil(180/8)
#define KNN_BLOCKS (NTI * NTJ)       // 276

// search radius: chord^2 = 0.0144 (r=0.12). E[nodes inside]=36.9;
// P(8th-NN beyond r) ~ 2e-9/gp; full-table fallback covers even that.
#define R2BOUND 0.0144f
#define RSNIP   0.121f               // r + slack for the patch filter

// workspace layout (bytes) — mesh2 region no longer used (R15: gemm folded
// into the interp kernel; algebraic identity W(sum wk m)+b = sum wk (Wm+b))
#define WS_W_OFF  0                            // float [G_TOT][8] weights
#define WS_I_OFF  (G_TOT * KNN * 4)            // int   [G_TOT][8] indices

typedef unsigned long long ull;

struct KnnSh {
    float4 cand[CAP];            // 23552
    int    cidx[CAP];            //  5888
    ull    lists[NW][64][KNN];   // 32768
    float4 gpp[64];              //  1024
    int    gorig[64];            //   256
    float  latv[TLA]; int lati[TLA];
    float  lonv[TLO]; int loni[TLO];
    float  axla[LATN];           //   364  lat staging
    float  axlo[LONN];           //   720  lon staging
    int    cnt; float r2tot;
};                               // ~64.7 KB (< 64 KiB static limit)

// ---------------------------------------------------------------------------
// kernel 0 (R15): knn ONLY — 276 blocks. The gemm path is removed (its work
// moved into kernel 1). The knn body is byte-identical to R12/R14.
// ---------------------------------------------------------------------------
__global__ __launch_bounds__(512) void knn_only(const float* __restrict__ mv,
                                                const float* __restrict__ lat,
                                                const float* __restrict__ lon,
                                                float* __restrict__ wts,
                                                int* __restrict__ nidx) {
    __shared__ __align__(16) char smem[sizeof(KnnSh)];
    const int blk = blockIdx.x, t = threadIdx.x;

    KnnSh& K = *reinterpret_cast<KnnSh*>(smem);
    const int gl = t & 63;
    const int w  = __builtin_amdgcn_readfirstlane(t >> 6);
    const int ti = blk / NTJ, tj = blk % NTJ;

    // ---- axis staging: lat on waves 0-1, lon on waves 4-6 (concurrent) ----
    if (t < LATN) K.axla[t] = lat[t];
    if (t >= 256 && t < 256 + LONN) K.axlo[t - 256] = lon[t - 256];
    __syncthreads();

    // ---- ranking: reads staged 8-deep (independent -> latency overlapped) ----
    if (t < LATN) {
        float v = K.axla[t];
        int r = 0;
        int j0 = 0;
        for (; j0 + 8 <= LATN; j0 += 8) {
            float o[8];
#pragma unroll
            for (int u = 0; u < 8; ++u) o[u] = K.axla[j0 + u];
#pragma unroll
            for (int u = 0; u < 8; ++u)
                r += (o[u] < v) || (o[u] == v && (j0 + u) < t);
        }
        for (; j0 < LATN; ++j0) {
            float o = K.axla[j0];
            r += (o < v) || (o == v && j0 < t);
        }
        int rr = r - ti * TLA;
        if (rr >= 0 && rr < TLA) { K.latv[rr] = v; K.lati[rr] = t; }
    }
    if (t >= 256 && t < 256 + LONN) {
        int tt = t - 256;
        float v = K.axlo[tt];
        int r = 0;
        int j0 = 0;
        for (; j0 + 8 <= LONN; j0 += 8) {
            float o[8];
#pragma unroll
            for (int u = 0; u < 8; ++u) o[u] = K.axlo[j0 + u];
#pragma unroll
            for (int u = 0; u < 8; ++u)
                r += (o[u] < v) || (o[u] == v && (j0 + u) < tt);
        }
        for (; j0 < LONN; ++j0) {
            float o = K.axlo[j0];
            r += (o < v) || (o == v && j0 < tt);
        }
        int rr = r - tj * TLO;
        if (rr >= 0 && rr < TLO) { K.lonv[rr] = v; K.loni[rr] = tt; }
    }
    __syncthreads();

    // ---- phase 0: gp coords (np-f32 exact), mapping ----
    if (t < 64) {
        if (t == 0) K.cnt = 0;
        int ar = ti * TLA + (t >> 3), orr = tj * TLO + (t & 7);
        bool val = (ar < LATN) && (orr < LONN);
        int a = min(ar, LATN - 1) - ti * TLA;   // clamped rank stays in window
        int o = min(orr, LONN - 1) - tj * TLO;
        double dla = (double)K.latv[a], dlo = (double)K.lonv[o];
        float cl = (float)cos(dla), sl = (float)sin(dla);
        float co = (float)cos(dlo), so = (float)sin(dlo);
        float gx = __fmul_rn(cl, co), gy = __fmul_rn(cl, so), gz = sl;
        float g2 = __fadd_rn(__fadd_rn(__fmul_rn(gx, gx), __fmul_rn(gy, gy)),
                             __fmul_rn(gz, gz));
        K.gpp[t]   = make_float4(gx, gy, gz, g2);
        K.gorig[t] = val ? (K.lati[a] * LONN + K.loni[o]) : -1;
    }
    __syncthreads();
    if (t < 64) {
        float4 c = K.gpp[27];
        float4 g = K.gpp[t];
        float dx = g.x - c.x, dy = g.y - c.y, dz = g.z - c.z;
        float d2c = dx * dx + dy * dy + dz * dz;
#pragma unroll
        for (int off = 32; off > 0; off >>= 1)
            d2c = fmaxf(d2c, __shfl_xor(d2c, off));
        if (t == 0) {
            float R = sqrtf(d2c) + RSNIP;
            K.r2tot = R * R + 1e-3f;
        }
    }
    __syncthreads();

    // ---- phase A: compaction from mv, loads staged 4-deep ----
    {
        float4 c = K.gpp[27];
        float r2t = K.r2tot;
        for (int j0 = t; j0 < N_NODES; j0 += 512 * 4) {
            float nx[4], ny[4], nz[4];
#pragma unroll
            for (int u = 0; u < 4; ++u) {
                int j = j0 + u * 512;
                int jj = (j < N_NODES) ? j : 0;
                nx[u] = mv[3 * jj + 0];
                ny[u] = mv[3 * jj + 1];
                nz[u] = mv[3 * jj + 2];
            }
#pragma unroll
            for (int u = 0; u < 4; ++u) {
                int j = j0 + u * 512;
                float dx = nx[u] - c.x, dy = ny[u] - c.y, dz = nz[u] - c.z;
                float d2c = dx * dx + dy * dy + dz * dz;
                if (d2c <= r2t && j < N_NODES) {
                    int pos = atomicAdd(&K.cnt, 1);
                    if (pos < CAP) {
                        // m2: byte-identical no-FMA sequence (np f32)
                        float m2 = __fadd_rn(__fadd_rn(__fmul_rn(nx[u], nx[u]),
                                                       __fmul_rn(ny[u], ny[u])),
                                             __fmul_rn(nz[u], nz[u]));
                        K.cand[pos] = make_float4(nx[u], ny[u], nz[u], m2);
                        K.cidx[pos] = j;
                    }
                }
            }
        }
    }
    __syncthreads();
    const int  ncand = K.cnt;
    const bool ovf   = ncand > CAP;

    // ---- phase B: per-lane top-8 (byte-for-byte R7..R14 logic) ----
    const float4 gme = K.gpp[gl];
    const float  gx = gme.x, gy = gme.y, gz = gme.z, g2 = gme.w;
    const float  ax = 2.0f * gx, ay = 2.0f * gy, az = 2.0f * gz;

    ull kk[KNN];
#pragma unroll
    for (int q = 0; q < KNN; ++q) kk[q] = ~0ull;

    if (!ovf) {
        const int nn = ncand;
        for (int ci = w; ci < nn; ci += NW) {
            float4 nd = K.cand[ci];
            int    j  = K.cidx[ci];
            float dot2 = __fmaf_rn(az, nd.z,
                          __fmaf_rn(ay, nd.y, __fmul_rn(ax, nd.x)));
            float d2 = __fsub_rn(__fadd_rn(g2, nd.w), dot2);
            if (d2 <= R2BOUND) {
                float sq = sqrtf(fmaxf(d2, 1e-12f));
                ull key = ((ull)__float_as_uint(sq) << 32) | (ull)(unsigned)j;
                if (key < kk[KNN - 1]) {
                    kk[KNN - 1] = key;
#pragma unroll
                    for (int q = KNN - 1; q > 0; --q) {
                        ull a = kk[q - 1], c = kk[q];
                        bool m = c < a;
                        kk[q - 1] = m ? c : a;
                        kk[q]     = m ? a : c;
                    }
                }
            }
        }
    } else {
        // cand overflow fallback (never expected): full mv scan, same key math
        for (int j = w * 1281; j < (w + 1) * 1281 && j < N_NODES; ++j) {
            float x = mv[3 * j], y = mv[3 * j + 1], z = mv[3 * j + 2];
            float m2 = __fadd_rn(__fadd_rn(__fmul_rn(x, x), __fmul_rn(y, y)),
                                 __fmul_rn(z, z));
            float dot2 = __fmaf_rn(az, z, __fmaf_rn(ay, y, __fmul_rn(ax, x)));
            float d2 = __fsub_rn(__fadd_rn(g2, m2), dot2);
            if (d2 <= R2BOUND) {
                float sq = sqrtf(fmaxf(d2, 1e-12f));
                ull key = ((ull)__float_as_uint(sq) << 32) | (ull)(unsigned)j;
                if (key < kk[KNN - 1]) {
                    kk[KNN - 1] = key;
#pragma unroll
                    for (int q = KNN - 1; q > 0; --q) {
                        ull a = kk[q - 1], c = kk[q];
                        bool m = c < a;
                        kk[q - 1] = m ? c : a;
                        kk[q]     = m ? a : c;
                    }
                }
            }
        }
    }

#pragma unroll
    for (int q = 0; q < KNN; ++q) K.lists[w][gl][q] = kk[q];
    __syncthreads();

    // ---- merge + softmax + scatter (byte-for-byte R7..R14) ----
    if (t < 64) {
        int g = K.gorig[t];
        if (g >= 0) {
            int pos[NW];
#pragma unroll
            for (int s = 0; s < NW; ++s) pos[s] = 0;
            float dist[KNN];
            int   idxs[KNN];
            bool  bad = false;
            for (int r = 0; r < KNN; ++r) {
                ull best = ~0ull;
                int bs = 0;
#pragma unroll
                for (int s = 0; s < NW; ++s) {
                    ull v = (pos[s] < KNN) ? K.lists[s][t][pos[s]] : ~0ull;
                    if (v < best) { best = v; bs = s; }
                }
                if (best == ~0ull) bad = true;
                dist[r] = __uint_as_float((unsigned)(best >> 32));
                idxs[r] = (int)(best & 0xFFFFFFFFULL);
#pragma unroll
                for (int s = 0; s < NW; ++s) pos[s] += (s == bs) ? 1 : 0;
            }
            if (bad) {
                // <8 in radius (P~2e-9/gp): per-gp brute force over mv
                float4 gm = K.gpp[t];
                float bx = 2.0f * gm.x, by = 2.0f * gm.y, bz = 2.0f * gm.z;
                ull mm[KNN];
#pragma unroll
                for (int q = 0; q < KNN; ++q) mm[q] = ~0ull;
                for (int j = 0; j < N_NODES; ++j) {
                    float x = mv[3 * j], y = mv[3 * j + 1], z = mv[3 * j + 2];
                    float m2 = __fadd_rn(__fadd_rn(__fmul_rn(x, x), __fmul_rn(y, y)),
                                         __fmul_rn(z, z));
                    float dot2 = __fmaf_rn(bz, z, __fmaf_rn(by, y, __fmul_rn(bx, x)));
                    float d2 = __fsub_rn(__fadd_rn(gm.w, m2), dot2);
                    float sq = sqrtf(fmaxf(d2, 1e-12f));
                    ull key = ((ull)__float_as_uint(sq) << 32) | (ull)(unsigned)j;
                    if (key < mm[KNN - 1]) {
                        mm[KNN - 1] = key;
#pragma unroll
                        for (int q = KNN - 1; q > 0; --q) {
                            ull a = mm[q - 1], c = mm[q];
                            bool m = c < a;
                            mm[q - 1] = m ? c : a;
                            mm[q]     = m ? a : c;
                        }
                    }
                }
#pragma unroll
                for (int r = 0; r < KNN; ++r) {
                    dist[r] = __uint_as_float((unsigned)(mm[r] >> 32));
                    idxs[r] = (int)(mm[r] & 0xFFFFFFFFULL);
                }
            }
            float e[KNN];
            float ssum = 0.f;
#pragma unroll
            for (int r = 0; r < KNN; ++r) {
                e[r] = expf(dist[0] - dist[r]);
                ssum += e[r];
            }
#pragma unroll
            for (int r = 0; r < KNN; ++r) {
                wts[g * KNN + r]  = e[r] / ssum;
                nidx[g * KNN + r] = idxs[r];
            }
        }
    }
}

// ---------------------------------------------------------------------------
// kernel 1 (R15): fused gather + W-transform. itp[g,c] = sum_k wk*mesh[b,id_k,c]
// (reference order: interpolate RAW mesh first), then
// out[b,cp,g] = sum_c W[cp][c]*itp[g][c] + bias[cp].
// Gather loop is byte-identical to R14's interp (just reading mesh, not mesh2).
// LDS: itpT padded to 67 (x3 mod 32 bijective -> conflict-free lane-private
// rows); W staged transposed [c][cp], read as float4 broadcast (free).
// Block mapping keeps R14's XCD-affine (b, tile) assignment.
// ---------------------------------------------------------------------------
__global__ __launch_bounds__(256) void itp_gemm(const float* __restrict__ mesh,
                                                const float* __restrict__ Wm,
                                                const float* __restrict__ bias,
                                                const float* __restrict__ wts,
                                                const int* __restrict__ nidx,
                                                float* __restrict__ out) {
    __shared__ float wT[64][68];    // [c][cp]  17408 B (rows 16B-aligned)
    __shared__ float itpT[64][67];  // [g][c]   17152 B (67: bank-bijective)
    __shared__ int   lidx[512];
    __shared__ float lwt[512];
    const int x    = blockIdx.x & 7;        // ~ XCD id (dispatch round-robin)
    const int ii   = blockIdx.x >> 3;       // 0..127
    const int b    = x >> 1;                // 2 XCDs per batch
    const int tile = (x & 1) * 128 + ii;    // 0..255, each (b,tile) once
    const int t  = threadIdx.x;
    const int wv = __builtin_amdgcn_readfirstlane(t >> 6);
    const int ln = t & 63;
    const int g0 = tile * 64;

#pragma unroll
    for (int r = 0; r < 2; ++r) {           // weights/indices for 64 gps
        int e  = r * 256 + t;
        int gc = min(g0 + (e >> 3), G_TOT - 1);
        int s  = gc * KNN + (e & 7);
        lidx[e] = nidx[s];
        lwt[e]  = wts[s];
    }
#pragma unroll
    for (int k2 = 0; k2 < 4; ++k2) {        // W: 64 rows x 16 float4, transposed
        int e = k2 * 256 + t;
        int r = e >> 4, c4 = e & 15;        // r == cp
        float4 wv4 = *(const float4*)&Wm[r * CH + c4 * 4];
        wT[c4 * 4 + 0][r] = wv4.x;
        wT[c4 * 4 + 1][r] = wv4.y;
        wT[c4 * 4 + 2][r] = wv4.z;
        wT[c4 * 4 + 3][r] = wv4.w;
    }
    __syncthreads();

    // ---- gather: itp[gloc][ln] = sum_k wk * mesh[b, id_k, ln] ----
    const float* mb = mesh + (size_t)b * N_NODES * CH;
#pragma unroll 4
    for (int gi = 0; gi < 16; ++gi) {
        int gloc = wv * 16 + gi;
        float acc = 0.f;
#pragma unroll
        for (int k = 0; k < KNN; ++k) {
            int   id = lidx[gloc * KNN + k];
            float wk = lwt[gloc * KNN + k];
            acc = fmaf(wk, mb[(size_t)id * CH + ln], acc);  // 256B/wave, ILP 8
        }
        itpT[gloc][ln] = acc;               // lanes -> distinct banks (x3 biject)
    }
    __syncthreads();

    // ---- transform: lane ln = g; wave wv owns cp block [wv*16, wv*16+16) ----
    float4 a0 = make_float4(0.f, 0.f, 0.f, 0.f);
    float4 a1 = a0, a2 = a0, a3 = a0;
    const int cp0 = wv * 16;
    for (int c = 0; c < CH; ++c) {
        float av = itpT[ln][c];             // lane-private row, conflict-free
        float4 w0 = *(const float4*)&wT[c][cp0 + 0];   // wave-uniform: broadcast
        float4 w1 = *(const float4*)&wT[c][cp0 + 4];
        float4 w2 = *(const float4*)&wT[c][cp0 + 8];
        float4 w3 = *(const float4*)&wT[c][cp0 + 12];
        a0.x = fmaf(av, w0.x, a0.x); a0.y = fmaf(av, w0.y, a0.y);
        a0.z = fmaf(av, w0.z, a0.z); a0.w = fmaf(av, w0.w, a0.w);
        a1.x = fmaf(av, w1.x, a1.x); a1.y = fmaf(av, w1.y, a1.y);
        a1.z = fmaf(av, w1.z, a1.z); a1.w = fmaf(av, w1.w, a1.w);
        a2.x = fmaf(av, w2.x, a2.x); a2.y = fmaf(av, w2.y, a2.y);
        a2.z = fmaf(av, w2.z, a2.z); a2.w = fmaf(av, w2.w, a2.w);
        a3.x = fmaf(av, w3.x, a3.x); a3.y = fmaf(av, w3.y, a3.y);
        a3.z = fmaf(av, w3.z, a3.z); a3.w = fmaf(av, w3.w, a3.w);
    }

    int g = g0 + ln;
    if (g < G_TOT) {
        const float4 b0 = *(const float4*)&bias[cp0 + 0];
        const float4 b1 = *(const float4*)&bias[cp0 + 4];
        const float4 b2 = *(const float4*)&bias[cp0 + 8];
        const float4 b3 = *(const float4*)&bias[cp0 + 12];
        float o[16] = {a0.x + b0.x, a0.y + b0.y, a0.z + b0.z, a0.w + b0.w,
                       a1.x + b1.x, a1.y + b1.y, a1.z + b1.z, a1.w + b1.w,
                       a2.x + b2.x, a2.y + b2.y, a2.z + b2.z, a2.w + b2.w,
                       a3.x + b3.x, a3.y + b3.y, a3.z + b3.z, a3.w + b3.w};
#pragma unroll
        for (int cs = 0; cs < 16; ++cs) {
            int cp = cp0 + cs;
            out[((size_t)b * CH + cp) * G_TOT + g] = o[cs];  // lanes: consecutive g
        }
    }
}

// ---------------------------------------------------------------------------
extern "C" void kernel_launch(void* const* d_in, const int* in_sizes, int n_in,
                              void* d_out, int out_size, void* d_ws, size_t ws_size,
                              hipStream_t stream) {
    const float* mesh = (const float*)d_in[0];  // [4][10242][64]
    const float* mv   = (const float*)d_in[1];  // [10242][3]
    const float* lat  = (const float*)d_in[2];  // [91]
    const float* lon  = (const float*)d_in[3];  // [180]
    const float* Wm   = (const float*)d_in[4];  // [64][64]
    const float* bias = (const float*)d_in[5];  // [64]
    float* out = (float*)d_out;                 // [4][64][91][180]

    float* wts = (float*)((char*)d_ws + WS_W_OFF);
    int*   nid = (int*)((char*)d_ws + WS_I_OFF);

    hipLaunchKernelGGL(knn_only, dim3(KNN_BLOCKS), dim3(512), 0, stream,
                       mv, lat, lon, wts, nid);
    hipLaunchKernelGGL(itp_gemm, dim3(NBATCH * 256), dim3(256), 0, stream,
                       mesh, Wm, bias, wts, nid, out);
}

// Round 4
// 117.395 us; speedup vs baseline: 1.0744x; 1.0744x over previous
//
#include <hip/hip_runtime.h>
#include <math.h>

#define G_TOT   16380
#define N_NODES 10242
#define LATN    91
#define LONN    180
#define CH      64
#define NBATCH  4
#define KNN     8

#define NW      8                    // waves per knn block
#define CAP     1472                 // LDS candidate capacity (expected ~300)
#define TLA     8
#define TLO     8
#define NTI     12                   // ceil(91/8)
#define NTJ     23                   // ceil(180/8)
#define KNN_BLOCKS (NTI * NTJ)       // 276
#define GEMM_TPB   81                // 128-row tiles per batch: ceil(10242/128)
#define GEMM_BLOCKS (NBATCH * GEMM_TPB)  // 324

// search radius: chord^2 = 0.0144 (r=0.12). E[nodes inside]=36.9;
// P(8th-NN beyond r) ~ 2e-9/gp; full-table fallback covers even that.
#define R2BOUND 0.0144f
#define RSNIP   0.121f               // r + slack for the patch filter

// workspace layout (bytes)
#define WS_W_OFF  0                            // float [G_TOT][8] weights
#define WS_I_OFF  (G_TOT * KNN * 4)            // int   [G_TOT][8] indices
#define WS_M2_OFF (2 * G_TOT * KNN * 4)        // float [4][N_NODES][64] mesh2

typedef unsigned long long ull;

// LDS overlays (shared via raw buffer; knn and gemm paths never coexist in a block)
struct KnnSh {
    float4 cand[CAP];            // 23552
    int    cidx[CAP];            //  5888
    ull    lists[NW][64][KNN];   // 32768
    float4 gpp[64];              //  1024
    int    gorig[64];            //   256
    float  latv[TLA]; int lati[TLA];
    float  lonv[TLO]; int loni[TLO];
    float  axla[LATN];           //   364  lat staging
    float  axlo[LONN];           //   720  lon staging
    int    cnt; float r2tot;
};                               // ~64.7 KB (< 64 KiB static limit)
struct GemmSh {
    float amT[64][132];          // 33792  amT[c][row]  (128-row tile)
    float wtT[64][68];           // 17408  wtT[c][cp]
};                               // ~51.2 KB

// ---------------------------------------------------------------------------
// kernel 0: blocks 0..275 = spatial-patch KNN; blocks 276..599 = mesh2 gemm.
// R16 = exact revert to the verified-best R12/R0 configuration (117.0 us).
// Rationale: R13 (coop fusion) failed; R14 (XCD affinity) +0.9 noise;
// R15 (gemm folded into interp) +8.8 regression — gemm work must stay
// CONCURRENT with knn (hidden under knn latency), not serial after it.
// ---------------------------------------------------------------------------
__global__ __launch_bounds__(512) void knn_gemm(const float* __restrict__ mv,
                                                const float* __restrict__ lat,
                                                const float* __restrict__ lon,
                                                const float* __restrict__ mesh,
                                                const float* __restrict__ Wm,
                                                const float* __restrict__ bias,
                                                float* __restrict__ mesh2,
                                                float* __restrict__ wts,
                                                int* __restrict__ nidx) {
    __shared__ __align__(16) char smem[sizeof(KnnSh)];
    const int blk = blockIdx.x, t = threadIdx.x;

    if (blk >= KNN_BLOCKS) {
        // ================= gemm path =================
        GemmSh& G = *reinterpret_cast<GemmSh*>(smem);
        const int gb   = blk - KNN_BLOCKS;
        const int b    = gb / GEMM_TPB;
        const int row0 = (gb % GEMM_TPB) * 128;
        const float* mb = mesh + (size_t)b * N_NODES * CH;

#pragma unroll
        for (int k2 = 0; k2 < 4; ++k2) {     // mesh tile: 128 rows x 16 float4
            int e = k2 * 512 + t;
            int r = e >> 4, c4 = e & 15;
            int row = row0 + r;
            float4 v = make_float4(0.f, 0.f, 0.f, 0.f);
            if (row < N_NODES) v = *(const float4*)&mb[(size_t)row * CH + c4 * 4];
            G.amT[c4 * 4 + 0][r] = v.x;
            G.amT[c4 * 4 + 1][r] = v.y;
            G.amT[c4 * 4 + 2][r] = v.z;
            G.amT[c4 * 4 + 3][r] = v.w;
        }
#pragma unroll
        for (int k2 = 0; k2 < 2; ++k2) {     // W: 64 rows x 16 float4
            int e = k2 * 512 + t;
            int r = e >> 4, c4 = e & 15;     // r == cp
            float4 wv = *(const float4*)&Wm[r * CH + c4 * 4];
            G.wtT[c4 * 4 + 0][r] = wv.x;
            G.wtT[c4 * 4 + 1][r] = wv.y;
            G.wtT[c4 * 4 + 2][r] = wv.z;
            G.wtT[c4 * 4 + 3][r] = wv.w;
        }
        __syncthreads();

        const int tr = t & 31, tc = t >> 5;
        const int r0 = tr * 4, cp0 = tc * 4;
        float acc[4][4];
#pragma unroll
        for (int i = 0; i < 4; ++i)
#pragma unroll
            for (int j = 0; j < 4; ++j) acc[i][j] = 0.f;

        for (int c = 0; c < 64; ++c) {
            float4 av = *(const float4*)&G.amT[c][r0];
            float4 wv = *(const float4*)&G.wtT[c][cp0];
            float a4[4] = {av.x, av.y, av.z, av.w};
            float w4[4] = {wv.x, wv.y, wv.z, wv.w};
#pragma unroll
            for (int i = 0; i < 4; ++i)
#pragma unroll
                for (int j = 0; j < 4; ++j)
                    acc[i][j] = fmaf(a4[i], w4[j], acc[i][j]);
        }

        float4 bv = *(const float4*)&bias[cp0];
#pragma unroll
        for (int i = 0; i < 4; ++i) {
            int row = row0 + r0 + i;
            if (row < N_NODES) {
                float4 o = make_float4(acc[i][0] + bv.x, acc[i][1] + bv.y,
                                       acc[i][2] + bv.z, acc[i][3] + bv.w);
                *(float4*)&mesh2[((size_t)b * N_NODES + row) * CH + cp0] = o;
            }
        }
        return;
    }

    // ================= knn path =================
    KnnSh& K = *reinterpret_cast<KnnSh*>(smem);
    const int gl = t & 63;
    const int w  = __builtin_amdgcn_readfirstlane(t >> 6);
    const int ti = blk / NTJ, tj = blk % NTJ;

    // ---- axis staging: lat on waves 0-1, lon on waves 4-6 (concurrent) ----
    if (t < LATN) K.axla[t] = lat[t];
    if (t >= 256 && t < 256 + LONN) K.axlo[t - 256] = lon[t - 256];
    __syncthreads();

    // ---- ranking: reads staged 8-deep (independent -> latency overlapped);
    //      same comparisons as R11 -> identical ranks ----
    if (t < LATN) {
        float v = K.axla[t];
        int r = 0;
        int j0 = 0;
        for (; j0 + 8 <= LATN; j0 += 8) {
            float o[8];
#pragma unroll
            for (int u = 0; u < 8; ++u) o[u] = K.axla[j0 + u];
#pragma unroll
            for (int u = 0; u < 8; ++u)
                r += (o[u] < v) || (o[u] == v && (j0 + u) < t);
        }
        for (; j0 < LATN; ++j0) {
            float o = K.axla[j0];
            r += (o < v) || (o == v && j0 < t);
        }
        int rr = r - ti * TLA;
        if (rr >= 0 && rr < TLA) { K.latv[rr] = v; K.lati[rr] = t; }
    }
    if (t >= 256 && t < 256 + LONN) {
        int tt = t - 256;
        float v = K.axlo[tt];
        int r = 0;
        int j0 = 0;
        for (; j0 + 8 <= LONN; j0 += 8) {
            float o[8];
#pragma unroll
            for (int u = 0; u < 8; ++u) o[u] = K.axlo[j0 + u];
#pragma unroll
            for (int u = 0; u < 8; ++u)
                r += (o[u] < v) || (o[u] == v && (j0 + u) < tt);
        }
        for (; j0 < LONN; ++j0) {
            float o = K.axlo[j0];
            r += (o < v) || (o == v && j0 < tt);
        }
        int rr = r - tj * TLO;
        if (rr >= 0 && rr < TLO) { K.lonv[rr] = v; K.loni[rr] = tt; }
    }
    __syncthreads();

    // ---- phase 0: gp coords (np-f32 exact), mapping ----
    if (t < 64) {
        if (t == 0) K.cnt = 0;
        int ar = ti * TLA + (t >> 3), orr = tj * TLO + (t & 7);
        bool val = (ar < LATN) && (orr < LONN);
        int a = min(ar, LATN - 1) - ti * TLA;   // clamped rank stays in window
        int o = min(orr, LONN - 1) - tj * TLO;
        double dla = (double)K.latv[a], dlo = (double)K.lonv[o];
        float cl = (float)cos(dla), sl = (float)sin(dla);
        float co = (float)cos(dlo), so = (float)sin(dlo);
        float gx = __fmul_rn(cl, co), gy = __fmul_rn(cl, so), gz = sl;
        float g2 = __fadd_rn(__fadd_rn(__fmul_rn(gx, gx), __fmul_rn(gy, gy)),
                             __fmul_rn(gz, gz));
        K.gpp[t]   = make_float4(gx, gy, gz, g2);
        K.gorig[t] = val ? (K.lati[a] * LONN + K.loni[o]) : -1;
    }
    __syncthreads();
    if (t < 64) {
        float4 c = K.gpp[27];
        float4 g = K.gpp[t];
        float dx = g.x - c.x, dy = g.y - c.y, dz = g.z - c.z;
        float d2c = dx * dx + dy * dy + dz * dz;
#pragma unroll
        for (int off = 32; off > 0; off >>= 1)
            d2c = fmaxf(d2c, __shfl_xor(d2c, off));
        if (t == 0) {
            float R = sqrtf(d2c) + RSNIP;
            K.r2tot = R * R + 1e-3f;
        }
    }
    __syncthreads();

    // ---- phase A: compaction from mv, loads staged 4-deep ----
    {
        float4 c = K.gpp[27];
        float r2t = K.r2tot;
        for (int j0 = t; j0 < N_NODES; j0 += 512 * 4) {
            float nx[4], ny[4], nz[4];
#pragma unroll
            for (int u = 0; u < 4; ++u) {
                int j = j0 + u * 512;
                int jj = (j < N_NODES) ? j : 0;
                nx[u] = mv[3 * jj + 0];
                ny[u] = mv[3 * jj + 1];
                nz[u] = mv[3 * jj + 2];
            }
#pragma unroll
            for (int u = 0; u < 4; ++u) {
                int j = j0 + u * 512;
                float dx = nx[u] - c.x, dy = ny[u] - c.y, dz = nz[u] - c.z;
                float d2c = dx * dx + dy * dy + dz * dz;
                if (d2c <= r2t && j < N_NODES) {
                    int pos = atomicAdd(&K.cnt, 1);
                    if (pos < CAP) {
                        // m2: byte-identical no-FMA sequence (np f32)
                        float m2 = __fadd_rn(__fadd_rn(__fmul_rn(nx[u], nx[u]),
                                                       __fmul_rn(ny[u], ny[u])),
                                             __fmul_rn(nz[u], nz[u]));
                        K.cand[pos] = make_float4(nx[u], ny[u], nz[u], m2);
                        K.cidx[pos] = j;
                    }
                }
            }
        }
    }
    __syncthreads();
    const int  ncand = K.cnt;
    const bool ovf   = ncand > CAP;

    // ---- phase B: per-lane top-8 (byte-for-byte R7/R10/R11 logic) ----
    const float4 gme = K.gpp[gl];
    const float  gx = gme.x, gy = gme.y, gz = gme.z, g2 = gme.w;
    const float  ax = 2.0f * gx, ay = 2.0f * gy, az = 2.0f * gz;

    ull kk[KNN];
#pragma unroll
    for (int q = 0; q < KNN; ++q) kk[q] = ~0ull;

    if (!ovf) {
        const int nn = ncand;
        for (int ci = w; ci < nn; ci += NW) {
            float4 nd = K.cand[ci];
            int    j  = K.cidx[ci];
            float dot2 = __fmaf_rn(az, nd.z,
                          __fmaf_rn(ay, nd.y, __fmul_rn(ax, nd.x)));
            float d2 = __fsub_rn(__fadd_rn(g2, nd.w), dot2);
            if (d2 <= R2BOUND) {
                float sq = sqrtf(fmaxf(d2, 1e-12f));
                ull key = ((ull)__float_as_uint(sq) << 32) | (ull)(unsigned)j;
                if (key < kk[KNN - 1]) {
                    kk[KNN - 1] = key;
#pragma unroll
                    for (int q = KNN - 1; q > 0; --q) {
                        ull a = kk[q - 1], c = kk[q];
                        bool m = c < a;
                        kk[q - 1] = m ? c : a;
                        kk[q]     = m ? a : c;
                    }
                }
            }
        }
    } else {
        // cand overflow fallback (never expected): full mv scan, same key math
        for (int j = w * 1281; j < (w + 1) * 1281 && j < N_NODES; ++j) {
            float x = mv[3 * j], y = mv[3 * j + 1], z = mv[3 * j + 2];
            float m2 = __fadd_rn(__fadd_rn(__fmul_rn(x, x), __fmul_rn(y, y)),
                                 __fmul_rn(z, z));
            float dot2 = __fmaf_rn(az, z, __fmaf_rn(ay, y, __fmul_rn(ax, x)));
            float d2 = __fsub_rn(__fadd_rn(g2, m2), dot2);
            if (d2 <= R2BOUND) {
                float sq = sqrtf(fmaxf(d2, 1e-12f));
                ull key = ((ull)__float_as_uint(sq) << 32) | (ull)(unsigned)j;
                if (key < kk[KNN - 1]) {
                    kk[KNN - 1] = key;
#pragma unroll
                    for (int q = KNN - 1; q > 0; --q) {
                        ull a = kk[q - 1], c = kk[q];
                        bool m = c < a;
                        kk[q - 1] = m ? c : a;
                        kk[q]     = m ? a : c;
                    }
                }
            }
        }
    }

#pragma unroll
    for (int q = 0; q < KNN; ++q) K.lists[w][gl][q] = kk[q];
    __syncthreads();

    // ---- merge + softmax + scatter (byte-for-byte R7/R10/R11) ----
    if (t < 64) {
        int g = K.gorig[t];
        if (g >= 0) {
            int pos[NW];
#pragma unroll
            for (int s = 0; s < NW; ++s) pos[s] = 0;
            float dist[KNN];
            int   idxs[KNN];
            bool  bad = false;
            for (int r = 0; r < KNN; ++r) {
                ull best = ~0ull;
                int bs = 0;
#pragma unroll
                for (int s = 0; s < NW; ++s) {
                    ull v = (pos[s] < KNN) ? K.lists[s][t][pos[s]] : ~0ull;
                    if (v < best) { best = v; bs = s; }
                }
                if (best == ~0ull) bad = true;
                dist[r] = __uint_as_float((unsigned)(best >> 32));
                idxs[r] = (int)(best & 0xFFFFFFFFULL);
#pragma unroll
                for (int s = 0; s < NW; ++s) pos[s] += (s == bs) ? 1 : 0;
            }
            if (bad) {
                // <8 in radius (P~2e-9/gp): per-gp brute force over mv
                float4 gm = K.gpp[t];
                float bx = 2.0f * gm.x, by = 2.0f * gm.y, bz = 2.0f * gm.z;
                ull mm[KNN];
#pragma unroll
                for (int q = 0; q < KNN; ++q) mm[q] = ~0ull;
                for (int j = 0; j < N_NODES; ++j) {
                    float x = mv[3 * j], y = mv[3 * j + 1], z = mv[3 * j + 2];
                    float m2 = __fadd_rn(__fadd_rn(__fmul_rn(x, x), __fmul_rn(y, y)),
                                         __fmul_rn(z, z));
                    float dot2 = __fmaf_rn(bz, z, __fmaf_rn(by, y, __fmul_rn(bx, x)));
                    float d2 = __fsub_rn(__fadd_rn(gm.w, m2), dot2);
                    float sq = sqrtf(fmaxf(d2, 1e-12f));
                    ull key = ((ull)__float_as_uint(sq) << 32) | (ull)(unsigned)j;
                    if (key < mm[KNN - 1]) {
                        mm[KNN - 1] = key;
#pragma unroll
                        for (int q = KNN - 1; q > 0; --q) {
                            ull a = mm[q - 1], c = mm[q];
                            bool m = c < a;
                            mm[q - 1] = m ? c : a;
                            mm[q]     = m ? a : c;
                        }
                    }
                }
#pragma unroll
                for (int r = 0; r < KNN; ++r) {
                    dist[r] = __uint_as_float((unsigned)(mm[r] >> 32));
                    idxs[r] = (int)(mm[r] & 0xFFFFFFFFULL);
                }
            }
            float e[KNN];
            float ssum = 0.f;
#pragma unroll
            for (int r = 0; r < KNN; ++r) {
                e[r] = expf(dist[0] - dist[r]);
                ssum += e[r];
            }
#pragma unroll
            for (int r = 0; r < KNN; ++r) {
                wts[g * KNN + r]  = e[r] / ssum;
                nidx[g * KNN + r] = idxs[r];
            }
        }
    }
}

// ---------------------------------------------------------------------------
// kernel 1: out[b,cp,g] = sum_k w_k * mesh2[b,idx_k,cp]  (bias folded into
// mesh2 since sum_k w_k == 1). Byte-identical to R10/R11/R12 interp_gather.
// ---------------------------------------------------------------------------
__global__ __launch_bounds__(256) void interp_gather(const float* __restrict__ mesh2,
                                                     const float* __restrict__ wts,
                                                     const int* __restrict__ nidx,
                                                     float* __restrict__ out) {
    __shared__ float lds2[64][66];  // [cp][g]
    __shared__ int   lidx[512];
    __shared__ float lwt[512];
    const int tile = blockIdx.x & 255;
    const int b    = blockIdx.x >> 8;
    const int t  = threadIdx.x;
    const int wv = __builtin_amdgcn_readfirstlane(t >> 6);
    const int ln = t & 63;
    const int g0 = tile * 64;

#pragma unroll
    for (int r = 0; r < 2; ++r) {
        int e  = r * 256 + t;
        int gc = min(g0 + (e >> 3), G_TOT - 1);
        int s  = gc * KNN + (e & 7);
        lidx[e] = nidx[s];
        lwt[e]  = wts[s];
    }
    __syncthreads();

    const float* m2b = mesh2 + (size_t)b * N_NODES * CH;
#pragma unroll 4
    for (int gi = 0; gi < 16; ++gi) {
        int gloc = wv * 16 + gi;
        float acc = 0.f;
#pragma unroll
        for (int k = 0; k < KNN; ++k) {
            int   id = lidx[gloc * KNN + k];
            float wk = lwt[gloc * KNN + k];
            acc = fmaf(wk, m2b[(size_t)id * CH + ln], acc);  // 256B/wave, ILP 8
        }
        lds2[ln][gloc] = acc;
    }
    __syncthreads();

    int g = g0 + ln;
    if (g < G_TOT) {
#pragma unroll
        for (int cs = 0; cs < 16; ++cs) {
            int cp = wv * 16 + cs;
            out[((size_t)b * CH + cp) * G_TOT + g] = lds2[cp][ln];
        }
    }
}

// ---------------------------------------------------------------------------
extern "C" void kernel_launch(void* const* d_in, const int* in_sizes, int n_in,
                              void* d_out, int out_size, void* d_ws, size_t ws_size,
                              hipStream_t stream) {
    const float* mesh = (const float*)d_in[0];  // [4][10242][64]
    const float* mv   = (const float*)d_in[1];  // [10242][3]
    const float* lat  = (const float*)d_in[2];  // [91]
    const float* lon  = (const float*)d_in[3];  // [180]
    const float* Wm   = (const float*)d_in[4];  // [64][64]
    const float* bias = (const float*)d_in[5];  // [64]
    float* out = (float*)d_out;                 // [4][64][91][180]

    float* wts = (float*)((char*)d_ws + WS_W_OFF);
    int*   nid = (int*)((char*)d_ws + WS_I_OFF);
    float* m2  = (float*)((char*)d_ws + WS_M2_OFF);

    hipLaunchKernelGGL(knn_gemm, dim3(KNN_BLOCKS + GEMM_BLOCKS), dim3(512), 0, stream,
                       mv, lat, lon, mesh, Wm, bias, m2, wts, nid);
    hipLaunchKernelGGL(interp_gather, dim3(NBATCH * 256), dim3(256), 0, stream,
                       m2, wts, nid, out);
}

// Round 5
// 117.056 us; speedup vs baseline: 1.0775x; 1.0029x over previous
//
#include <hip/hip_runtime.h>
#include <math.h>

#define G_TOT   16380
#define N_NODES 10242
#define LATN    91
#define LONN    180
#define CH      64
#define NBATCH  4
#define KNN     8

#define NW      8                    // waves per knn block
#define CAP     1472                 // LDS candidate capacity (expected ~300)
#define TLA     8
#define TLO     8
#define NTI     12                   // ceil(91/8)
#define NTJ     23                   // ceil(180/8)
#define KNN_BLOCKS (NTI * NTJ)       // 276
#define GEMM_TPB   81                // 128-row tiles per batch: ceil(10242/128)
#define GEMM_BLOCKS (NBATCH * GEMM_TPB)  // 324

// search radius: chord^2 = 0.0144 (r=0.12). E[nodes inside]=36.9;
// P(8th-NN beyond r) ~ 2e-9/gp; full-table fallback covers even that.
#define R2BOUND 0.0144f
#define RSNIP   0.121f               // r + slack for the patch filter

// workspace layout (bytes)
#define WS_W_OFF  0                            // float [G_TOT][8] weights
#define WS_I_OFF  (G_TOT * KNN * 4)            // int   [G_TOT][8] indices
#define WS_M2_OFF (2 * G_TOT * KNN * 4)        // float [4][N_NODES][64] mesh2

typedef unsigned long long ull;

// LDS overlays (shared via raw buffer; knn and gemm paths never coexist in a block)
struct KnnSh {
    float4 cand[CAP];            // 23552
    int    cidx[CAP];            //  5888
    ull    lists[NW][64][KNN];   // 32768
    float4 gpp[64];              //  1024
    int    gorig[64];            //   256
    float  latv[TLA]; int lati[TLA];
    float  lonv[TLO]; int loni[TLO];
    float  axla[LATN];           //   364  lat staging
    float  axlo[LONN];           //   720  lon staging
    int    cnt; float r2tot;
};                               // ~64.7 KB (< 64 KiB static limit)
struct GemmSh {
    float amT[64][132];          // 33792  amT[c][row]  (128-row tile)
    float wtT[64][68];           // 17408  wtT[c][cp]
};                               // ~51.2 KB

// ---------------------------------------------------------------------------
// kernel 0: blocks 0..275 = spatial-patch KNN; blocks 276..599 = mesh2 gemm.
// R17 change vs R16 (ONE LINE): __launch_bounds__(512, 4) — min 4 waves/EU
// caps VGPRs at 128 so 2 blocks fit per CU (LDS already allows it:
// 2 x 64.7KB <= 160KB). Theory: without the cap the compiler exceeds 128
// VGPRs -> 1 block/CU -> the 600-block grid needs ~3 sequential scheduling
// rounds, knn blocks landing in rounds 1 AND 2 (~2x block latency) — the
// ~30us of "unexplained" kernel-0 time. All arithmetic byte-identical R16.
// ---------------------------------------------------------------------------
__global__ __launch_bounds__(512, 4) void knn_gemm(const float* __restrict__ mv,
                                                   const float* __restrict__ lat,
                                                   const float* __restrict__ lon,
                                                   const float* __restrict__ mesh,
                                                   const float* __restrict__ Wm,
                                                   const float* __restrict__ bias,
                                                   float* __restrict__ mesh2,
                                                   float* __restrict__ wts,
                                                   int* __restrict__ nidx) {
    __shared__ __align__(16) char smem[sizeof(KnnSh)];
    const int blk = blockIdx.x, t = threadIdx.x;

    if (blk >= KNN_BLOCKS) {
        // ================= gemm path =================
        GemmSh& G = *reinterpret_cast<GemmSh*>(smem);
        const int gb   = blk - KNN_BLOCKS;
        const int b    = gb / GEMM_TPB;
        const int row0 = (gb % GEMM_TPB) * 128;
        const float* mb = mesh + (size_t)b * N_NODES * CH;

#pragma unroll
        for (int k2 = 0; k2 < 4; ++k2) {     // mesh tile: 128 rows x 16 float4
            int e = k2 * 512 + t;
            int r = e >> 4, c4 = e & 15;
            int row = row0 + r;
            float4 v = make_float4(0.f, 0.f, 0.f, 0.f);
            if (row < N_NODES) v = *(const float4*)&mb[(size_t)row * CH + c4 * 4];
            G.amT[c4 * 4 + 0][r] = v.x;
            G.amT[c4 * 4 + 1][r] = v.y;
            G.amT[c4 * 4 + 2][r] = v.z;
            G.amT[c4 * 4 + 3][r] = v.w;
        }
#pragma unroll
        for (int k2 = 0; k2 < 2; ++k2) {     // W: 64 rows x 16 float4
            int e = k2 * 512 + t;
            int r = e >> 4, c4 = e & 15;     // r == cp
            float4 wv = *(const float4*)&Wm[r * CH + c4 * 4];
            G.wtT[c4 * 4 + 0][r] = wv.x;
            G.wtT[c4 * 4 + 1][r] = wv.y;
            G.wtT[c4 * 4 + 2][r] = wv.z;
            G.wtT[c4 * 4 + 3][r] = wv.w;
        }
        __syncthreads();

        const int tr = t & 31, tc = t >> 5;
        const int r0 = tr * 4, cp0 = tc * 4;
        float acc[4][4];
#pragma unroll
        for (int i = 0; i < 4; ++i)
#pragma unroll
            for (int j = 0; j < 4; ++j) acc[i][j] = 0.f;

        for (int c = 0; c < 64; ++c) {
            float4 av = *(const float4*)&G.amT[c][r0];
            float4 wv = *(const float4*)&G.wtT[c][cp0];
            float a4[4] = {av.x, av.y, av.z, av.w};
            float w4[4] = {wv.x, wv.y, wv.z, wv.w};
#pragma unroll
            for (int i = 0; i < 4; ++i)
#pragma unroll
                for (int j = 0; j < 4; ++j)
                    acc[i][j] = fmaf(a4[i], w4[j], acc[i][j]);
        }

        float4 bv = *(const float4*)&bias[cp0];
#pragma unroll
        for (int i = 0; i < 4; ++i) {
            int row = row0 + r0 + i;
            if (row < N_NODES) {
                float4 o = make_float4(acc[i][0] + bv.x, acc[i][1] + bv.y,
                                       acc[i][2] + bv.z, acc[i][3] + bv.w);
                *(float4*)&mesh2[((size_t)b * N_NODES + row) * CH + cp0] = o;
            }
        }
        return;
    }

    // ================= knn path =================
    KnnSh& K = *reinterpret_cast<KnnSh*>(smem);
    const int gl = t & 63;
    const int w  = __builtin_amdgcn_readfirstlane(t >> 6);
    const int ti = blk / NTJ, tj = blk % NTJ;

    // ---- axis staging: lat on waves 0-1, lon on waves 4-6 (concurrent) ----
    if (t < LATN) K.axla[t] = lat[t];
    if (t >= 256 && t < 256 + LONN) K.axlo[t - 256] = lon[t - 256];
    __syncthreads();

    // ---- ranking: reads staged 8-deep (independent -> latency overlapped);
    //      same comparisons as R11 -> identical ranks ----
    if (t < LATN) {
        float v = K.axla[t];
        int r = 0;
        int j0 = 0;
        for (; j0 + 8 <= LATN; j0 += 8) {
            float o[8];
#pragma unroll
            for (int u = 0; u < 8; ++u) o[u] = K.axla[j0 + u];
#pragma unroll
            for (int u = 0; u < 8; ++u)
                r += (o[u] < v) || (o[u] == v && (j0 + u) < t);
        }
        for (; j0 < LATN; ++j0) {
            float o = K.axla[j0];
            r += (o < v) || (o == v && j0 < t);
        }
        int rr = r - ti * TLA;
        if (rr >= 0 && rr < TLA) { K.latv[rr] = v; K.lati[rr] = t; }
    }
    if (t >= 256 && t < 256 + LONN) {
        int tt = t - 256;
        float v = K.axlo[tt];
        int r = 0;
        int j0 = 0;
        for (; j0 + 8 <= LONN; j0 += 8) {
            float o[8];
#pragma unroll
            for (int u = 0; u < 8; ++u) o[u] = K.axlo[j0 + u];
#pragma unroll
            for (int u = 0; u < 8; ++u)
                r += (o[u] < v) || (o[u] == v && (j0 + u) < tt);
        }
        for (; j0 < LONN; ++j0) {
            float o = K.axlo[j0];
            r += (o < v) || (o == v && j0 < tt);
        }
        int rr = r - tj * TLO;
        if (rr >= 0 && rr < TLO) { K.lonv[rr] = v; K.loni[rr] = tt; }
    }
    __syncthreads();

    // ---- phase 0: gp coords (np-f32 exact), mapping ----
    if (t < 64) {
        if (t == 0) K.cnt = 0;
        int ar = ti * TLA + (t >> 3), orr = tj * TLO + (t & 7);
        bool val = (ar < LATN) && (orr < LONN);
        int a = min(ar, LATN - 1) - ti * TLA;   // clamped rank stays in window
        int o = min(orr, LONN - 1) - tj * TLO;
        double dla = (double)K.latv[a], dlo = (double)K.lonv[o];
        float cl = (float)cos(dla), sl = (float)sin(dla);
        float co = (float)cos(dlo), so = (float)sin(dlo);
        float gx = __fmul_rn(cl, co), gy = __fmul_rn(cl, so), gz = sl;
        float g2 = __fadd_rn(__fadd_rn(__fmul_rn(gx, gx), __fmul_rn(gy, gy)),
                             __fmul_rn(gz, gz));
        K.gpp[t]   = make_float4(gx, gy, gz, g2);
        K.gorig[t] = val ? (K.lati[a] * LONN + K.loni[o]) : -1;
    }
    __syncthreads();
    if (t < 64) {
        float4 c = K.gpp[27];
        float4 g = K.gpp[t];
        float dx = g.x - c.x, dy = g.y - c.y, dz = g.z - c.z;
        float d2c = dx * dx + dy * dy + dz * dz;
#pragma unroll
        for (int off = 32; off > 0; off >>= 1)
            d2c = fmaxf(d2c, __shfl_xor(d2c, off));
        if (t == 0) {
            float R = sqrtf(d2c) + RSNIP;
            K.r2tot = R * R + 1e-3f;
        }
    }
    __syncthreads();

    // ---- phase A: compaction from mv, loads staged 4-deep ----
    {
        float4 c = K.gpp[27];
        float r2t = K.r2tot;
        for (int j0 = t; j0 < N_NODES; j0 += 512 * 4) {
            float nx[4], ny[4], nz[4];
#pragma unroll
            for (int u = 0; u < 4; ++u) {
                int j = j0 + u * 512;
                int jj = (j < N_NODES) ? j : 0;
                nx[u] = mv[3 * jj + 0];
                ny[u] = mv[3 * jj + 1];
                nz[u] = mv[3 * jj + 2];
            }
#pragma unroll
            for (int u = 0; u < 4; ++u) {
                int j = j0 + u * 512;
                float dx = nx[u] - c.x, dy = ny[u] - c.y, dz = nz[u] - c.z;
                float d2c = dx * dx + dy * dy + dz * dz;
                if (d2c <= r2t && j < N_NODES) {
                    int pos = atomicAdd(&K.cnt, 1);
                    if (pos < CAP) {
                        // m2: byte-identical no-FMA sequence (np f32)
                        float m2 = __fadd_rn(__fadd_rn(__fmul_rn(nx[u], nx[u]),
                                                       __fmul_rn(ny[u], ny[u])),
                                             __fmul_rn(nz[u], nz[u]));
                        K.cand[pos] = make_float4(nx[u], ny[u], nz[u], m2);
                        K.cidx[pos] = j;
                    }
                }
            }
        }
    }
    __syncthreads();
    const int  ncand = K.cnt;
    const bool ovf   = ncand > CAP;

    // ---- phase B: per-lane top-8 (byte-for-byte R7/R10/R11 logic) ----
    const float4 gme = K.gpp[gl];
    const float  gx = gme.x, gy = gme.y, gz = gme.z, g2 = gme.w;
    const float  ax = 2.0f * gx, ay = 2.0f * gy, az = 2.0f * gz;

    ull kk[KNN];
#pragma unroll
    for (int q = 0; q < KNN; ++q) kk[q] = ~0ull;

    if (!ovf) {
        const int nn = ncand;
        for (int ci = w; ci < nn; ci += NW) {
            float4 nd = K.cand[ci];
            int    j  = K.cidx[ci];
            float dot2 = __fmaf_rn(az, nd.z,
                          __fmaf_rn(ay, nd.y, __fmul_rn(ax, nd.x)));
            float d2 = __fsub_rn(__fadd_rn(g2, nd.w), dot2);
            if (d2 <= R2BOUND) {
                float sq = sqrtf(fmaxf(d2, 1e-12f));
                ull key = ((ull)__float_as_uint(sq) << 32) | (ull)(unsigned)j;
                if (key < kk[KNN - 1]) {
                    kk[KNN - 1] = key;
#pragma unroll
                    for (int q = KNN - 1; q > 0; --q) {
                        ull a = kk[q - 1], c = kk[q];
                        bool m = c < a;
                        kk[q - 1] = m ? c : a;
                        kk[q]     = m ? a : c;
                    }
                }
            }
        }
    } else {
        // cand overflow fallback (never expected): full mv scan, same key math
        for (int j = w * 1281; j < (w + 1) * 1281 && j < N_NODES; ++j) {
            float x = mv[3 * j], y = mv[3 * j + 1], z = mv[3 * j + 2];
            float m2 = __fadd_rn(__fadd_rn(__fmul_rn(x, x), __fmul_rn(y, y)),
                                 __fmul_rn(z, z));
            float dot2 = __fmaf_rn(az, z, __fmaf_rn(ay, y, __fmul_rn(ax, x)));
            float d2 = __fsub_rn(__fadd_rn(g2, m2), dot2);
            if (d2 <= R2BOUND) {
                float sq = sqrtf(fmaxf(d2, 1e-12f));
                ull key = ((ull)__float_as_uint(sq) << 32) | (ull)(unsigned)j;
                if (key < kk[KNN - 1]) {
                    kk[KNN - 1] = key;
#pragma unroll
                    for (int q = KNN - 1; q > 0; --q) {
                        ull a = kk[q - 1], c = kk[q];
                        bool m = c < a;
                        kk[q - 1] = m ? c : a;
                        kk[q]     = m ? a : c;
                    }
                }
            }
        }
    }

#pragma unroll
    for (int q = 0; q < KNN; ++q) K.lists[w][gl][q] = kk[q];
    __syncthreads();

    // ---- merge + softmax + scatter (byte-for-byte R7/R10/R11) ----
    if (t < 64) {
        int g = K.gorig[t];
        if (g >= 0) {
            int pos[NW];
#pragma unroll
            for (int s = 0; s < NW; ++s) pos[s] = 0;
            float dist[KNN];
            int   idxs[KNN];
            bool  bad = false;
            for (int r = 0; r < KNN; ++r) {
                ull best = ~0ull;
                int bs = 0;
#pragma unroll
                for (int s = 0; s < NW; ++s) {
                    ull v = (pos[s] < KNN) ? K.lists[s][t][pos[s]] : ~0ull;
                    if (v < best) { best = v; bs = s; }
                }
                if (best == ~0ull) bad = true;
                dist[r] = __uint_as_float((unsigned)(best >> 32));
                idxs[r] = (int)(best & 0xFFFFFFFFULL);
#pragma unroll
                for (int s = 0; s < NW; ++s) pos[s] += (s == bs) ? 1 : 0;
            }
            if (bad) {
                // <8 in radius (P~2e-9/gp): per-gp brute force over mv
                float4 gm = K.gpp[t];
                float bx = 2.0f * gm.x, by = 2.0f * gm.y, bz = 2.0f * gm.z;
                ull mm[KNN];
#pragma unroll
                for (int q = 0; q < KNN; ++q) mm[q] = ~0ull;
                for (int j = 0; j < N_NODES; ++j) {
                    float x = mv[3 * j], y = mv[3 * j + 1], z = mv[3 * j + 2];
                    float m2 = __fadd_rn(__fadd_rn(__fmul_rn(x, x), __fmul_rn(y, y)),
                                         __fmul_rn(z, z));
                    float dot2 = __fmaf_rn(bz, z, __fmaf_rn(by, y, __fmul_rn(bx, x)));
                    float d2 = __fsub_rn(__fadd_rn(gm.w, m2), dot2);
                    float sq = sqrtf(fmaxf(d2, 1e-12f));
                    ull key = ((ull)__float_as_uint(sq) << 32) | (ull)(unsigned)j;
                    if (key < mm[KNN - 1]) {
                        mm[KNN - 1] = key;
#pragma unroll
                        for (int q = KNN - 1; q > 0; --q) {
                            ull a = mm[q - 1], c = mm[q];
                            bool m = c < a;
                            mm[q - 1] = m ? c : a;
                            mm[q]     = m ? a : c;
                        }
                    }
                }
#pragma unroll
                for (int r = 0; r < KNN; ++r) {
                    dist[r] = __uint_as_float((unsigned)(mm[r] >> 32));
                    idxs[r] = (int)(mm[r] & 0xFFFFFFFFULL);
                }
            }
            float e[KNN];
            float ssum = 0.f;
#pragma unroll
            for (int r = 0; r < KNN; ++r) {
                e[r] = expf(dist[0] - dist[r]);
                ssum += e[r];
            }
#pragma unroll
            for (int r = 0; r < KNN; ++r) {
                wts[g * KNN + r]  = e[r] / ssum;
                nidx[g * KNN + r] = idxs[r];
            }
        }
    }
}

// ---------------------------------------------------------------------------
// kernel 1: out[b,cp,g] = sum_k w_k * mesh2[b,idx_k,cp]  (bias folded into
// mesh2 since sum_k w_k == 1). Byte-identical to R10/R11/R12/R16.
// ---------------------------------------------------------------------------
__global__ __launch_bounds__(256) void interp_gather(const float* __restrict__ mesh2,
                                                     const float* __restrict__ wts,
                                                     const int* __restrict__ nidx,
                                                     float* __restrict__ out) {
    __shared__ float lds2[64][66];  // [cp][g]
    __shared__ int   lidx[512];
    __shared__ float lwt[512];
    const int tile = blockIdx.x & 255;
    const int b    = blockIdx.x >> 8;
    const int t  = threadIdx.x;
    const int wv = __builtin_amdgcn_readfirstlane(t >> 6);
    const int ln = t & 63;
    const int g0 = tile * 64;

#pragma unroll
    for (int r = 0; r < 2; ++r) {
        int e  = r * 256 + t;
        int gc = min(g0 + (e >> 3), G_TOT - 1);
        int s  = gc * KNN + (e & 7);
        lidx[e] = nidx[s];
        lwt[e]  = wts[s];
    }
    __syncthreads();

    const float* m2b = mesh2 + (size_t)b * N_NODES * CH;
#pragma unroll 4
    for (int gi = 0; gi < 16; ++gi) {
        int gloc = wv * 16 + gi;
        float acc = 0.f;
#pragma unroll
        for (int k = 0; k < KNN; ++k) {
            int   id = lidx[gloc * KNN + k];
            float wk = lwt[gloc * KNN + k];
            acc = fmaf(wk, m2b[(size_t)id * CH + ln], acc);  // 256B/wave, ILP 8
        }
        lds2[ln][gloc] = acc;
    }
    __syncthreads();

    int g = g0 + ln;
    if (g < G_TOT) {
#pragma unroll
        for (int cs = 0; cs < 16; ++cs) {
            int cp = wv * 16 + cs;
            out[((size_t)b * CH + cp) * G_TOT + g] = lds2[cp][ln];
        }
    }
}

// ---------------------------------------------------------------------------
extern "C" void kernel_launch(void* const* d_in, const int* in_sizes, int n_in,
                              void* d_out, int out_size, void* d_ws, size_t ws_size,
                              hipStream_t stream) {
    const float* mesh = (const float*)d_in[0];  // [4][10242][64]
    const float* mv   = (const float*)d_in[1];  // [10242][3]
    const float* lat  = (const float*)d_in[2];  // [91]
    const float* lon  = (const float*)d_in[3];  // [180]
    const float* Wm   = (const float*)d_in[4];  // [64][64]
    const float* bias = (const float*)d_in[5];  // [64]
    float* out = (float*)d_out;                 // [4][64][91][180]

    float* wts = (float*)((char*)d_ws + WS_W_OFF);
    int*   nid = (int*)((char*)d_ws + WS_I_OFF);
    float* m2  = (float*)((char*)d_ws + WS_M2_OFF);

    hipLaunchKernelGGL(knn_gemm, dim3(KNN_BLOCKS + GEMM_BLOCKS), dim3(512), 0, stream,
                       mv, lat, lon, mesh, Wm, bias, m2, wts, nid);
    hipLaunchKernelGGL(interp_gather, dim3(NBATCH * 256), dim3(256), 0, stream,
                       m2, wts, nid, out);
}